// Round 10
// baseline (216.678 us; speedup 1.0000x reference)
//
#include <hip/hip_runtime.h>
#include <hip/hip_bf16.h>

#define NPOS 4096          // 64*64 positions
#define CD   64            // channels
#define NB   4             // batch
#define PADW 66
#define PADN (66*66)       // padded positions (zero halo)
#define LOG2E 1.4426950408889634f

extern "C" __device__ float __ocml_exp2_f32(float);

typedef __bf16 bf16x8_t __attribute__((ext_vector_type(8)));
typedef float  f32x4_t  __attribute__((ext_vector_type(4)));
typedef float  f32x16_t __attribute__((ext_vector_type(16)));

static __device__ __forceinline__ unsigned short f2bf(float f) {
    return __builtin_bit_cast(unsigned short, __float2bfloat16(f));
}
static __device__ __forceinline__ float bf2f(unsigned short u) {
    return __builtin_bit_cast(float, (unsigned)u << 16);
}

static __device__ __forceinline__ void gload_lds16(const void* g, void* l) {
    __builtin_amdgcn_global_load_lds(
        (const __attribute__((address_space(1))) void*)g,
        (__attribute__((address_space(3))) void*)l, 16, 0, 0);
}

static __device__ __forceinline__ unsigned cvtpk_bf16(float lo, float hi) {
    unsigned r;
    asm("v_cvt_pk_bf16_f32 %0, %1, %2" : "=v"(r) : "v"(lo), "v"(hi));
    return r;
}

// ---------------------------------------------------------------------------
// prep: fused {halo-zero, weight-repack, input-pack} in one launch.
// grid 672 = 16 halo + 144 wrepack + 512 pack. block 256.
// ---------------------------------------------------------------------------
__global__ __launch_bounds__(256) void prep_kernel(
    const float* __restrict__ x, const float* __restrict__ y,
    const float* __restrict__ qw, const float* __restrict__ rkw,
    const float* __restrict__ rvw, const float* __restrict__ ikw,
    const float* __restrict__ ivw, const float* __restrict__ srw,
    const float* __restrict__ qs, const float* __restrict__ rks,
    const float* __restrict__ rvs, const float* __restrict__ iks,
    const float* __restrict__ ivs, const float* __restrict__ srs,
    unsigned short* __restrict__ pads, unsigned short* __restrict__ Wf)
{
    const int bx = blockIdx.x;
    if (bx < 16) {
        unsigned short* p = pads + (size_t)bx * PADN * CD;
        const uint4 z = make_uint4(0, 0, 0, 0);
        for (int idx = threadIdx.x; idx < 260 * 8; idx += 256) {
            const int pi = idx >> 3, chn = idx & 7;
            int pos;
            if (pi < 66)       pos = pi;
            else if (pi < 132) pos = 65 * PADW + (pi - 66);
            else { const int rem = pi - 132;
                   pos = (1 + (rem >> 1)) * PADW + ((rem & 1) ? 65 : 0); }
            *(uint4*)(p + (size_t)pos * CD + chn * 8) = z;
        }
        return;
    }
    if (bx < 160) {
        const int f = bx - 16;
        const float* w; const float* s; int cin, local;
        if (f < 36)       { w = qw;  s = qs;  cin = 128; local = f; }
        else if (f < 54)  { w = rkw; s = rks; cin = 64;  local = f - 36; }
        else if (f < 72)  { w = rvw; s = rvs; cin = 64;  local = f - 54; }
        else if (f < 90)  { w = ikw; s = iks; cin = 64;  local = f - 72; }
        else if (f < 108) { w = ivw; s = ivs; cin = 64;  local = f - 90; }
        else              { w = srw; s = srs; cin = 128; local = f - 108; }
        const int src = (cin == 128) ? local / 18 : 0;
        const int rem = (cin == 128) ? local % 18 : local;
        const int tap = rem >> 1, kt = rem & 1;
        const int t = threadIdx.x, cot = t >> 6, l = t & 63;
        const int co = cot * 16 + (l & 15);
        const float kmul = ((f >= 36 && f < 54) || (f >= 72 && f < 90)) ? LOG2E : 1.0f;
        const float sc = s[co] * kmul;
        unsigned short us[8];
#pragma unroll
        for (int e = 0; e < 8; ++e) {
            const int ci = src * 64 + kt * 32 + ((l >> 4) * 8) + e;
            us[e] = f2bf(w[((size_t)co * cin + ci) * 9 + tap] * sc);
        }
        *(uint4*)(Wf + ((size_t)(f * 4 + cot) * 64 + l) * 8) = *(uint4*)us;
        return;
    }
    {
        const int idx = bx - 160;
        const int h = idx & 63, b = (idx >> 6) & 3, src = idx >> 8;
        const float* in = src ? y : x;
        unsigned short* out = pads + (size_t)src * NB * PADN * CD;
        __shared__ float t[64][65];
        const int tt = threadIdx.x;
        {
            const int ci = tt >> 2, w0 = (tt & 3) * 16;
            const float* p = in + ((size_t)b * 64 + ci) * NPOS + h * 64 + w0;
#pragma unroll
            for (int j = 0; j < 16; j += 4) {
                float4 v = *(const float4*)(p + j);
                t[ci][w0 + j] = v.x; t[ci][w0 + j + 1] = v.y;
                t[ci][w0 + j + 2] = v.z; t[ci][w0 + j + 3] = v.w;
            }
        }
        __syncthreads();
        const int w = tt >> 2, c0 = (tt & 3) * 16;
        unsigned short us[16];
#pragma unroll
        for (int j = 0; j < 16; ++j) us[j] = f2bf(t[c0 + j][w]);
        unsigned short* q = out + ((size_t)b * PADN + (h + 1) * PADW + (w + 1)) * CD + c0;
        *(uint4*)q = *(uint4*)us;
        *(uint4*)(q + 8) = *(uint4*)(us + 8);
    }
}

// ---------------------------------------------------------------------------
// Implicit-GEMM conv3x3 via MFMA — A-tile AND weights in LDS (r8 version).
// ---------------------------------------------------------------------------
__global__ __launch_bounds__(256) void conv_mfma_kernel(
    const unsigned short* __restrict__ xpad, const unsigned short* __restrict__ ypad,
    const unsigned short* __restrict__ rpadR, const unsigned short* __restrict__ rpadI,
    const unsigned short* __restrict__ Wf,
    const float* __restrict__ qb, const float* __restrict__ rkb,
    const float* __restrict__ rvb, const float* __restrict__ ikb,
    const float* __restrict__ ivb, const float* __restrict__ srb,
    unsigned short* __restrict__ Qt, unsigned short* __restrict__ KtR,
    unsigned short* __restrict__ VR, unsigned short* __restrict__ KtI,
    unsigned short* __restrict__ VI, float* __restrict__ outf,
    int convid_base)
{
    const int conv = convid_base + (blockIdx.z >> 1);
    const int ch   = blockIdx.z & 1;            // co half
    const int hg = blockIdx.x, b = blockIdx.y;
    const unsigned short *in0, *in1; const float* bias;
    int nsrc, wfbase, layout; void* outp;
    switch (conv) {
        case 0:  in0 = xpad;  in1 = ypad;  nsrc = 2; wfbase = 0;   bias = qb;  outp = Qt;  layout = 0; break;
        case 1:  in0 = xpad;  in1 = 0;     nsrc = 1; wfbase = 36;  bias = rkb; outp = KtR; layout = 0; break;
        case 2:  in0 = xpad;  in1 = 0;     nsrc = 1; wfbase = 54;  bias = rvb; outp = VR;  layout = 1; break;
        case 3:  in0 = ypad;  in1 = 0;     nsrc = 1; wfbase = 72;  bias = ikb; outp = KtI; layout = 0; break;
        case 4:  in0 = ypad;  in1 = 0;     nsrc = 1; wfbase = 90;  bias = ivb; outp = VI;  layout = 1; break;
        default: in0 = rpadR; in1 = rpadI; nsrc = 2; wfbase = 108; bias = srb; outp = outf; layout = 2; break;
    }
    const float bmul = (conv == 1 || conv == 3) ? LOG2E : 1.0f;
    const int tid = threadIdx.x;
    const int lane = tid & 63, wv = tid >> 6;
    const int l15 = lane & 15, g = lane >> 4;
    const int rr = wv >> 1;                     // wave's output row (0/1)
    const int wseg = (wv & 1) * 32;             // wave's pos segment

    __shared__ unsigned short As[264 * 64];     // 4 rows x 66 pos x 64c = 33.8KB
    __shared__ unsigned short Wl[36 * 512];     // 36 slots x 1KB = 36KB

    f32x4_t acc[2][2];                          // [pf][cc]
#pragma unroll
    for (int i = 0; i < 2; ++i)
#pragma unroll
        for (int j = 0; j < 2; ++j) acc[i][j] = (f32x4_t){0.f, 0.f, 0.f, 0.f};

    for (int src = 0; src < nsrc; ++src) {
        if (src) __syncthreads();               // readers of prev src done
        const unsigned short* tsrc =
            (src ? in1 : in0) + ((size_t)b * PADN + (size_t)hg * 2 * PADW) * CD;
        for (int k = 0; k < 2112; k += 256) {
            const int idx = k + tid;
            if (idx < 2112) {                   // wave-uniform tail
                const int s = (idx & ~7) | ((idx ^ (idx >> 3)) & 7);
                gload_lds16(tsrc + (size_t)s * 8, As + (size_t)(idx & ~63) * 8);
            }
        }
#pragma unroll
        for (int j = 0; j < 9; ++j) {
            const int slot = wv * 9 + j;
            const int fg = wfbase + src * 18 + (slot >> 1);
            gload_lds16(Wf + ((size_t)(fg * 4 + ch * 2 + (slot & 1)) * 64 + lane) * 8,
                        Wl + slot * 512);
        }
        __syncthreads();                        // stage visible (vmcnt drained)
#pragma unroll
        for (int ky = 0; ky < 3; ++ky) {
#pragma unroll
            for (int kx = 0; kx < 3; ++kx) {
#pragma unroll
                for (int kt = 0; kt < 2; ++kt) {
                    const int fj = (ky * 3 + kx) * 2 + kt;
                    bf16x8_t a[2];
#pragma unroll
                    for (int pf = 0; pf < 2; ++pf) {
                        const int P = (rr + ky) * 66 + wseg + pf * 16 + kx + l15;
                        const int q = (kt * 4 + g) ^ (P & 7);
                        a[pf] = *(const bf16x8_t*)(As + P * 64 + q * 8);
                    }
#pragma unroll
                    for (int cc = 0; cc < 2; ++cc) {
                        bf16x8_t wfr = *(const bf16x8_t*)(Wl + (size_t)(fj * 2 + cc) * 512 + lane * 8);
                        acc[0][cc] = __builtin_amdgcn_mfma_f32_16x16x32_bf16(a[0], wfr, acc[0][cc], 0, 0, 0);
                        acc[1][cc] = __builtin_amdgcn_mfma_f32_16x16x32_bf16(a[1], wfr, acc[1][cc], 0, 0, 0);
                    }
                }
            }
        }
    }

    const int hrow = hg * 2 + rr;
#pragma unroll
    for (int pf = 0; pf < 2; ++pf) {
        const int nb4 = hrow * 64 + wseg + pf * 16 + g * 4;
        if (layout == 0) {
            unsigned short* o = (unsigned short*)outp + (size_t)b * NPOS * CD;
#pragma unroll
            for (int cc = 0; cc < 2; ++cc) {
                const int co = (ch * 2 + cc) * 16 + l15;
                const float bv = bias[co] * bmul;
#pragma unroll
                for (int r = 0; r < 4; ++r)
                    o[(size_t)(nb4 + r) * CD + co] = f2bf(fmaxf(acc[pf][cc][r] + bv, 0.f));
            }
        } else if (layout == 1) {
            unsigned short* o = (unsigned short*)outp + (size_t)b * CD * NPOS;
#pragma unroll
            for (int cc = 0; cc < 2; ++cc) {
                const int cch = (ch * 2 + cc) * 16 + l15;
                const float bv = bias[cch];
                unsigned short us[4];
#pragma unroll
                for (int r = 0; r < 4; ++r) us[r] = f2bf(fmaxf(acc[pf][cc][r] + bv, 0.f));
                *(uint2*)(o + (size_t)cch * NPOS + nb4) = *(uint2*)us;
            }
        } else {
            float* o = (float*)outp + (size_t)b * CD * NPOS;
#pragma unroll
            for (int cc = 0; cc < 2; ++cc) {
                const int cch = (ch * 2 + cc) * 16 + l15;
                const float bv = bias[cch];
                f32x4_t v;
#pragma unroll
                for (int r = 0; r < 4; ++r) v[r] = fmaxf(acc[pf][cc][r] + bv, 0.f);
                *(f32x4_t*)(o + (size_t)cch * NPOS + nb4) = v;
            }
        }
    }
}

// ---------------------------------------------------------------------------
// Flash attention — 32x32x16 MFMA, runtime n-split, bf16 partials.
// grid 32*NB*2*nseg blocks: fid&1=att, (fid>>1)&3=b (fid&7 = XCD group),
// (fid>>3)&(nseg-1)=seg, mblk=fid>>(3+lg). block 256 = 4 waves x 32 m.
// Opart bf16 [att][b][seg][m][c]; ml fp32 [att][b][seg][m][2] (base-2 m, l).
// ---------------------------------------------------------------------------
__global__ __launch_bounds__(256, 4) void attn_kernel(
    const unsigned short* __restrict__ Qt,
    const unsigned short* __restrict__ KtR, const unsigned short* __restrict__ KtI,
    const unsigned short* __restrict__ VR,  const unsigned short* __restrict__ VI,
    unsigned short* __restrict__ Opart, float* __restrict__ ml,
    int nseg, int lg, int nt)
{
    const int fid = blockIdx.x;
    const int att = fid & 1;
    const int b   = (fid >> 1) & 3;
    const int seg = (fid >> 3) & (nseg - 1);
    const int mblk = fid >> (3 + lg);
    const int lane = threadIdx.x & 63, wv = threadIdx.x >> 6;
    const int l31 = lane & 31, hi = lane >> 5;
    const int m0w = mblk * 128 + wv * 32;       // wave's m base

    const unsigned short* Qb = Qt + (size_t)b * NPOS * CD;
    const unsigned short* Kb = (att ? KtI : KtR) + (size_t)b * NPOS * CD;
    const unsigned short* Vb = (att ? VI : VR) + (size_t)b * CD * NPOS;

    __shared__ unsigned short Qs[2][64 * 64];
    __shared__ unsigned short Vs[2][64 * 64];

    // persistent K B-frags: col m = l31, k = kq*16 + hi*8 + e
    const unsigned short* kbase = Kb + (size_t)(m0w + l31) * CD + hi * 8;
    bf16x8_t fK[4];
#pragma unroll
    for (int kq = 0; kq < 4; ++kq)
        fK[kq] = *(const bf16x8_t*)(kbase + kq * 16);

    f32x16_t Oa, Ob2;
#pragma unroll
    for (int i = 0; i < 16; ++i) { Oa[i] = 0.f; Ob2[i] = 0.f; }
    float mrun = -3.0e38f, lsum = 0.f;

    const int csw = (lane & 7) ^ ((lane >> 3) & 7);   // staging source chunk
    const int nbase = seg << (12 - lg);               // seg * (NPOS/nseg)

    const int rq = wv * 16 + (lane >> 3);
    const unsigned short* qsrc0 = Qb + (size_t)(nbase + rq) * CD + csw * 8;
    const unsigned short* qsrc1 = qsrc0 + (size_t)8 * CD;
    const unsigned short* vsrc0 = Vb + (size_t)rq * NPOS + nbase + csw * 8;
    const unsigned short* vsrc1 = vsrc0 + (size_t)8 * NPOS;
    unsigned short* qdst = &Qs[0][(wv * 16) * 64];
    unsigned short* vdst = &Vs[0][(wv * 16) * 64];

#define STAGE(buf, itv) do {                                                  \
        const size_t qo = (size_t)(itv) * (64 * CD);                          \
        const size_t vo = (size_t)(itv) * 64;                                 \
        gload_lds16(qsrc0 + qo, qdst + (buf) * 4096);                         \
        gload_lds16(qsrc1 + qo, qdst + (buf) * 4096 + 512);                   \
        gload_lds16(vsrc0 + vo, vdst + (buf) * 4096);                         \
        gload_lds16(vsrc1 + vo, vdst + (buf) * 4096 + 512);                   \
    } while (0)

    STAGE(0, 0);

    const int r0x = l31 & 7;                    // read-XOR key (row&7)

    for (int it = 0; it < nt; ++it) {
        const int cur = it & 1;
        __syncthreads();   // drains stage(cur) DMAs; prev-iter reads done
        if (it + 1 < nt) STAGE(cur ^ 1, it + 1);

        // ---- QK^T: St[n][m], A = Q rows n (two 32-blocks), B = fK ----
        f32x16_t StA, StB;
#pragma unroll
        for (int i = 0; i < 16; ++i) { StA[i] = 0.f; StB[i] = 0.f; }
        const unsigned short* qsl = Qs[cur];
        __builtin_amdgcn_s_setprio(1);
#pragma unroll
        for (int kq = 0; kq < 4; ++kq) {
            const int chunk = ((kq << 1) | hi) ^ r0x;
            bf16x8_t a0 = *(const bf16x8_t*)(qsl + (size_t)l31 * 64 + chunk * 8);
            bf16x8_t a1 = *(const bf16x8_t*)(qsl + (size_t)(32 + l31) * 64 + chunk * 8);
            StA = __builtin_amdgcn_mfma_f32_32x32x16_bf16(a0, fK[kq], StA, 0, 0, 0);
            StB = __builtin_amdgcn_mfma_f32_32x32x16_bf16(a1, fK[kq], StB, 0, 0, 0);
        }
        __builtin_amdgcn_s_setprio(0);

        // ---- online softmax (base-2, defer-max); lane owns m = m0w+l31 ----
        float tmax = StA[0];
#pragma unroll
        for (int r = 0; r < 16; r += 2)
            tmax = fmaxf(fmaxf(tmax, StA[r]), StA[r + 1]);
#pragma unroll
        for (int r = 0; r < 16; r += 2)
            tmax = fmaxf(fmaxf(tmax, StB[r]), StB[r + 1]);
        if (!__all(tmax <= mrun + 12.0f)) {
            const float tr = fmaxf(tmax, __shfl_xor(tmax, 32));
            const float mnew = fmaxf(mrun, tr);
            const float corr = __builtin_amdgcn_exp2f(mrun - mnew);
            lsum *= corr;
#pragma unroll
            for (int i = 0; i < 16; ++i) { Oa[i] *= corr; Ob2[i] *= corr; }
            mrun = mnew;
        }

        // ---- exp + pack to PV B-frags via cvt_pk + permlane32_swap ----
        unsigned fr[4][4];
#pragma unroll
        for (int nb = 0; nb < 2; ++nb) {
            float p[16];
#pragma unroll
            for (int r = 0; r < 16; ++r) {
                p[r] = __builtin_amdgcn_exp2f((nb ? StB[r] : StA[r]) - mrun);
                lsum += p[r];
            }
#pragma unroll
            for (int hf = 0; hf < 2; ++hf) {
                unsigned u0 = cvtpk_bf16(p[8 * hf + 0], p[8 * hf + 1]);
                unsigned u1 = cvtpk_bf16(p[8 * hf + 2], p[8 * hf + 3]);
                unsigned v0 = cvtpk_bf16(p[8 * hf + 4], p[8 * hf + 5]);
                unsigned v1 = cvtpk_bf16(p[8 * hf + 6], p[8 * hf + 7]);
                asm volatile("v_permlane32_swap_b32 %0, %1" : "+v"(u0), "+v"(v0));
                asm volatile("v_permlane32_swap_b32 %0, %1" : "+v"(u1), "+v"(v1));
                fr[nb * 2 + hf][0] = u0; fr[nb * 2 + hf][1] = u1;
                fr[nb * 2 + hf][2] = v0; fr[nb * 2 + hf][3] = v1;
            }
        }

        // ---- PV: O[c][m] += V[c][n] P[m][n]; A = V rows c from LDS ----
        const unsigned short* vsl = Vs[cur];
        __builtin_amdgcn_s_setprio(1);
#pragma unroll
        for (int nq = 0; nq < 4; ++nq) {
            union { unsigned u[4]; bf16x8_t v; } bfr;
            bfr.u[0] = fr[nq][0]; bfr.u[1] = fr[nq][1];
            bfr.u[2] = fr[nq][2]; bfr.u[3] = fr[nq][3];
            const int chunk = ((nq << 1) | hi) ^ r0x;
            bf16x8_t av0 = *(const bf16x8_t*)(vsl + (size_t)l31 * 64 + chunk * 8);
            bf16x8_t av1 = *(const bf16x8_t*)(vsl + (size_t)(32 + l31) * 64 + chunk * 8);
            Oa  = __builtin_amdgcn_mfma_f32_32x32x16_bf16(av0, bfr.v, Oa, 0, 0, 0);
            Ob2 = __builtin_amdgcn_mfma_f32_32x32x16_bf16(av1, bfr.v, Ob2, 0, 0, 0);
        }
        __builtin_amdgcn_s_setprio(0);
    }

    // ---- epilogue: bf16 partials ----
    const float lred = lsum + __shfl_xor(lsum, 32);
    const int m = m0w + l31;
    unsigned short* Ob16 =
        Opart + ((((size_t)att * NB + b) * nseg + seg) * NPOS + m) * CD;
#pragma unroll
    for (int q = 0; q < 4; ++q) {
        uint2 w0 = make_uint2(cvtpk_bf16(Oa[4 * q], Oa[4 * q + 1]),
                              cvtpk_bf16(Oa[4 * q + 2], Oa[4 * q + 3]));
        uint2 w1 = make_uint2(cvtpk_bf16(Ob2[4 * q], Ob2[4 * q + 1]),
                              cvtpk_bf16(Ob2[4 * q + 2], Ob2[4 * q + 3]));
        *(uint2*)(Ob16 + 8 * q + 4 * hi) = w0;
        *(uint2*)(Ob16 + 32 + 8 * q + 4 * hi) = w1;
    }
    if (hi == 0) {
        float* mlb = ml + ((((size_t)att * NB + b) * nseg + seg) * NPOS + m) * 2;
        mlb[0] = mrun; mlb[1] = lred;
    }
#undef STAGE
}

// ---------------------------------------------------------------------------
// Combine nseg partials (bf16) -> refine = gamma*O/L + resid, bf16 into
// padded layout for the SR conv. grid (256 mtile16, NB, 2 att). Base-2.
// Two-pass over s (max, then weighted sum) to avoid runtime-indexed arrays.
// ---------------------------------------------------------------------------
__global__ __launch_bounds__(256) void combine_kernel(
    const unsigned short* __restrict__ Opart, const float* __restrict__ ml,
    const float* __restrict__ x, const float* __restrict__ y,
    const float* __restrict__ g1, const float* __restrict__ g2,
    unsigned short* __restrict__ rpadR, unsigned short* __restrict__ rpadI,
    int nseg)
{
    const int mt = blockIdx.x, b = blockIdx.y, att = blockIdx.z;
    const float* resid = att ? x : y;
    const float gamma = att ? g2[0] : g1[0];
    unsigned short* rp = (att ? rpadI : rpadR) + (size_t)b * PADN * CD;
    __shared__ float t[64][17];
    const int tt = threadIdx.x;
    {
        const int c = tt >> 2, m4 = (tt & 3) * 4;
        const float4 v = *(const float4*)(resid + ((size_t)b * CD + c) * NPOS + mt * 16 + m4);
        t[c][m4] = v.x; t[c][m4 + 1] = v.y; t[c][m4 + 2] = v.z; t[c][m4 + 3] = v.w;
    }
    __syncthreads();
    const int c = tt & 63, mq = tt >> 6;
    const size_t ob = ((size_t)att * NB + b) * nseg * (size_t)NPOS * CD;
    const size_t mb = ((size_t)att * NB + b) * nseg * (size_t)NPOS;
#pragma unroll
    for (int p = 0; p < 4; ++p) {
        const int mloc = mq * 4 + p;
        const int m = mt * 16 + mloc;
        float M = -3.0e38f;
        for (int s = 0; s < nseg; ++s)
            M = fmaxf(M, ml[(mb + (size_t)s * NPOS + m) * 2]);
        float Ov = 0.f, L = 0.f;
        for (int s = 0; s < nseg; ++s) {
            const float mm = ml[(mb + (size_t)s * NPOS + m) * 2];
            const float lv = ml[(mb + (size_t)s * NPOS + m) * 2 + 1];
            const float wgt = __ocml_exp2_f32(mm - M);
            L += wgt * lv;
            Ov += wgt * bf2f(Opart[ob + ((size_t)s * NPOS + m) * CD + c]);
        }
        const float val = fmaf(gamma, Ov / L, t[c][mloc]);
        const int h = m >> 6, w_ = m & 63;
        rp[((size_t)((h + 1) * PADW) + (w_ + 1)) * CD + c] = f2bf(val);
    }
}

// ---------------------------------------------------------------------------
extern "C" void kernel_launch(void* const* d_in, const int* in_sizes, int n_in,
                              void* d_out, int out_size, void* d_ws, size_t ws_size,
                              hipStream_t stream)
{
    const float* x    = (const float*)d_in[0];
    const float* y    = (const float*)d_in[1];
    const float* q_w  = (const float*)d_in[2];
    const float* q_s  = (const float*)d_in[3];
    const float* q_b  = (const float*)d_in[4];
    const float* rk_w = (const float*)d_in[5];
    const float* rk_s = (const float*)d_in[6];
    const float* rk_b = (const float*)d_in[7];
    const float* rv_w = (const float*)d_in[8];
    const float* rv_s = (const float*)d_in[9];
    const float* rv_b = (const float*)d_in[10];
    const float* ik_w = (const float*)d_in[11];
    const float* ik_s = (const float*)d_in[12];
    const float* ik_b = (const float*)d_in[13];
    const float* iv_w = (const float*)d_in[14];
    const float* iv_s = (const float*)d_in[15];
    const float* iv_b = (const float*)d_in[16];
    const float* sr_w = (const float*)d_in[17];
    const float* sr_s = (const float*)d_in[18];
    const float* sr_b = (const float*)d_in[19];
    const float* g1   = (const float*)d_in[20];
    const float* g2   = (const float*)d_in[21];

    const int nseg = 8, lg = 3, nt = NPOS / nseg / 64;

    char* ws = (char*)d_ws;
    size_t off = 0;
    auto alloc = [&](size_t bytes) {
        void* p = ws + off; off += (bytes + 255) & ~(size_t)255; return p;
    };
    const size_t PADB = (size_t)NB * PADN * CD * 2;
    unsigned short* xpad  = (unsigned short*)alloc(PADB);
    unsigned short* ypad  = (unsigned short*)alloc(PADB);
    unsigned short* rpadR = (unsigned short*)alloc(PADB);
    unsigned short* rpadI = (unsigned short*)alloc(PADB);
    unsigned short* Qt  = (unsigned short*)alloc((size_t)NB * NPOS * CD * 2);
    unsigned short* KtR = (unsigned short*)alloc((size_t)NB * NPOS * CD * 2);
    unsigned short* KtI = (unsigned short*)alloc((size_t)NB * NPOS * CD * 2);
    unsigned short* VR  = (unsigned short*)alloc((size_t)NB * NPOS * CD * 2);
    unsigned short* VI  = (unsigned short*)alloc((size_t)NB * NPOS * CD * 2);
    unsigned short* Wf  = (unsigned short*)alloc((size_t)144 * 4 * 64 * 16);
    unsigned short* Opart = (unsigned short*)alloc((size_t)2 * NB * nseg * NPOS * CD * 2);
    float* mlb = (float*)alloc((size_t)2 * NB * nseg * NPOS * 2 * 4);

    // prep x2 (dup isolates prep cost in total-time delta; idempotent)
    prep_kernel<<<dim3(672), 256, 0, stream>>>(
        x, y, q_w, rk_w, rv_w, ik_w, iv_w, sr_w,
        q_s, rk_s, rv_s, ik_s, iv_s, sr_s, xpad, Wf);
    prep_kernel<<<dim3(672), 256, 0, stream>>>(
        x, y, q_w, rk_w, rv_w, ik_w, iv_w, sr_w,
        q_s, rk_s, rv_s, ik_s, iv_s, sr_s, xpad, Wf);
    // 5 pre-attention convs (A-LDS + W-LDS), co-split
    conv_mfma_kernel<<<dim3(32, NB, 10), 256, 0, stream>>>(
        xpad, ypad, rpadR, rpadI, Wf,
        q_b, rk_b, rv_b, ik_b, iv_b, sr_b,
        Qt, KtR, VR, KtI, VI, nullptr, 0);
    // 32 mblk x 4 b x 2 att x nseg
    attn_kernel<<<dim3(32 * NB * 2 * nseg), 256, 0, stream>>>(
        Qt, KtR, KtI, VR, VI, Opart, mlb, nseg, lg, nt);
    // combine x2 (dup isolates combine cost; idempotent)
    combine_kernel<<<dim3(256, NB, 2), 256, 0, stream>>>(
        Opart, mlb, x, y, g1, g2, rpadR, rpadI, nseg);
    combine_kernel<<<dim3(256, NB, 2), 256, 0, stream>>>(
        Opart, mlb, x, y, g1, g2, rpadR, rpadI, nseg);
    // final SR conv -> d_out fp32 NCHW
    conv_mfma_kernel<<<dim3(32, NB, 2), 256, 0, stream>>>(
        xpad, ypad, rpadR, rpadI, Wf,
        q_b, rk_b, rv_b, ik_b, iv_b, sr_b,
        Qt, KtR, VR, KtI, VI, (float*)d_out, 5);
}